// Round 4
// baseline (148.555 us; speedup 1.0000x reference)
//
#include <hip/hip_runtime.h>
#include <math.h>

#define NUM_A 90
#define RBINS 727      // 2*363 + 1
#define HDIM  256
#define WDIM  256
#define RMIN  181      // lowest bin ever touched
#define RACT  365      // active bins: 181..545
#define BINS_PAD 368
#define STRIPS 4
#define GRP (BINS_PAD * STRIPS)   // 1472 threads per (b,a) = 23 waves exactly

// ---------------- angle table: tab[2a]=cos, tab[2a+1]=sin ----------------
__global__ void angles_k(float* __restrict__ tab) {
    int a = threadIdx.x;
    if (a < NUM_A) {
        double th = (double)a * (3.14159265358979323846 / 90.0);
        tab[2 * a]     = (float)cos(th);
        tab[2 * a + 1] = (float)sin(th);
    }
}

// ---------------- transpose: maskT[b][x][y] = mask[b][y][x] ----------------
__global__ __launch_bounds__(256) void transpose_k(const float* __restrict__ in,
                                                   float* __restrict__ out) {
    __shared__ float tile[32][33];
    int b = blockIdx.z;
    const float* ib = in  + (size_t)b * (HDIM * WDIM);
    float*       ob = out + (size_t)b * (HDIM * WDIM);
    int x0 = blockIdx.x * 32, y0 = blockIdx.y * 32;
    int tx = threadIdx.x, ty = threadIdx.y;
#pragma unroll
    for (int j = ty; j < 32; j += 8)
        tile[j][tx] = ib[(size_t)(y0 + j) * WDIM + (x0 + tx)];
    __syncthreads();
#pragma unroll
    for (int j = ty; j < 32; j += 8)
        ob[(size_t)(x0 + j) * HDIM + (y0 + tx)] = tile[tx][j];
}

// 12-byte vector load (global_load_dwordx3), 4-byte aligned
typedef float f3v __attribute__((ext_vector_type(3)));
typedef f3v __attribute__((aligned(4))) f3u;

// ---------------- gather hough, strip-split ----------------
// out[ba, r] = sum_{i,j} m * max(0, 1 - |t - r|), t = (i-128)ci + (j-128)cj + 363.
// Lane owns (bin r, strip m of 4); loops its quarter of the active j-range.
// Per row: i0 = clamp(ceil(lo), 0, 253); 3 taps i0..i0+2 with triangle weights
// clamp(1-|u|) that self-guard both the window edge and the image edge.
template<bool FAST>
__global__ __launch_bounds__(256) void hough_g_k(const float* __restrict__ srcA,
                                                 const float* __restrict__ srcB,
                                                 const float* __restrict__ tab,
                                                 float* __restrict__ out,
                                                 int nba) {
    int gtid = blockIdx.x * 256 + threadIdx.x;
    int grp  = gtid / GRP;                 // wave-uniform (GRP % 64 == 0)
    if (grp >= nba) return;
    int k    = gtid - grp * GRP;
    int ba   = __builtin_amdgcn_readfirstlane(grp);
    int b    = ba / NUM_A;
    int a    = ba - b * NUM_A;

    float c, s;
    if (FAST) { c = tab[2 * a]; s = tab[2 * a + 1]; }
    else {
        double th = (double)a * (3.14159265358979323846 / 90.0);
        c = (float)cos(th); s = (float)sin(th);
    }

    bool  xs = fabsf(c) >= fabsf(s);       // solve axis = larger coeff
    float ci = xs ? c : s;
    float cj = xs ? s : c;
    const float* src = (FAST ? (xs ? srcA : srcB) : srcA) + (size_t)b * (HDIM * WDIM);

    int   bin = k >> 2;                    // STRIPS = 4
    int   m   = k & 3;
    int   r   = RMIN + bin;
    float rf  = (float)r;
    bool  active = bin < RACT;

    // active j-range: rows whose in-image t-span [base+p, base+q] hits (r-1,r+1)
    float inv  = 1.0f / ci;                // |ci| >= 0.707
    float ainv = fabsf(inv);
    float p = fminf(-128.0f * ci, 127.0f * ci);
    float q = fmaxf(-128.0f * ci, 127.0f * ci);
    int jl, jh;
    float acj = fabsf(cj);
    if (acj > 1e-5f) {
        float invj = 1.0f / cj;
        float jA = (rf + 1.0f - p - 363.0f) * invj + 128.0f;
        float jB = (rf - 1.0f - q - 363.0f) * invj + 128.0f;
        float jmn = fminf(jA, jB) - 1.0f;   // widen: weights self-guard extras
        float jmx = fmaxf(jA, jB) + 2.0f;
        jl = (int)fminf(fmaxf(jmn, 0.0f), 256.0f);
        jh = (int)fminf(fmaxf(jmx, 0.0f), 256.0f);
    } else {                               // a = 0 or 45: t j-independent
        bool any = (363.0f + q > rf - 1.01f) && (363.0f + p < rf + 1.01f);
        jl = 0; jh = any ? 256 : 0;
    }
    if (!active) { jl = 0; jh = 0; }
    int len = jh - jl;                     // >= 0
    int js  = jl + ((m * len) >> 2);
    int je  = jl + (((m + 1) * len) >> 2);

    // lo(j) = LO0 + j*dlo (lower i-edge of window), z2(j) = Z0 + j*cj
    // (u0 = i0*ci + z2 = t(i0,j) - r). fma-from-base: no drift over rows.
    float dlo = -cj * inv;
    float LO0 = 128.0f + (rf - 363.0f) * inv - ainv + 128.0f * cj * inv;
    float Z0  = 363.0f - rf - 128.0f * cj - 128.0f * ci;
    float ci2 = ci + ci;

    float acc = 0.0f;
    for (int j = js; j < je; ++j) {
        float jf  = (float)j;
        float lo  = fmaf(jf, dlo, LO0);
        float z2  = fmaf(jf, cj, Z0);
        float i0f = __builtin_amdgcn_fmed3f(ceilf(lo), 0.0f, 253.0f);
        int   i0  = (int)i0f;
        float u0  = fmaf(i0f, ci, z2);
        float u1  = u0 + ci;
        float u2  = u0 + ci2;
        float w0 = fminf(fmaxf(1.0f - fabsf(u0), 0.0f), 1.0f);  // clamp-mod
        float w1 = fminf(fmaxf(1.0f - fabsf(u1), 0.0f), 1.0f);
        float w2 = fminf(fmaxf(1.0f - fabsf(u2), 0.0f), 1.0f);
        float m0, m1, m2;
        if (FAST || xs) {                  // solve axis contiguous
            f3v mm = *(const f3u*)(src + ((size_t)j << 8) + i0);
            m0 = mm.x; m1 = mm.y; m2 = mm.z;
        } else {                           // fallback: strided
            const float* cp = src + j + ((size_t)i0 << 8);
            m0 = cp[0]; m1 = cp[256]; m2 = cp[512];
        }
        acc = fmaf(m0, w0, acc);
        acc = fmaf(m1, w1, acc);
        acc = fmaf(m2, w2, acc);
    }

    // reduce the 4 strips (adjacent lanes), lane m==0 stores
    acc += __shfl_xor(acc, 1);
    acc += __shfl_xor(acc, 2);
    if (active && m == 0)
        out[(size_t)ba * RBINS + r] = acc;
}

extern "C" void kernel_launch(void* const* d_in, const int* in_sizes, int n_in,
                              void* d_out, int out_size, void* d_ws, size_t ws_size,
                              hipStream_t stream) {
    const float* mask = (const float*)d_in[0];
    float* out = (float*)d_out;
    int B = in_sizes[0] / (HDIM * WDIM);   // 16
    int nba = B * NUM_A;

    size_t needT = (size_t)B * HDIM * WDIM * sizeof(float);
    size_t needW = needT + 2 * NUM_A * sizeof(float);
    int fast = (d_ws != nullptr && ws_size >= needW) ? 1 : 0;
    float* maskT = (float*)d_ws;
    float* tab   = (float*)((char*)d_ws + needT);

    // zero the never-touched rho bins once per call (also covers len==0 bins)
    hipMemsetAsync(d_out, 0, (size_t)out_size * sizeof(float), stream);

    int nthreads = nba * GRP;
    int nblk = (nthreads + 255) / 256;

    if (fast) {
        transpose_k<<<dim3(WDIM / 32, HDIM / 32, B), dim3(32, 8), 0, stream>>>(mask, maskT);
        angles_k<<<1, 128, 0, stream>>>(tab);
        hough_g_k<true><<<nblk, 256, 0, stream>>>(mask, maskT, tab, out, nba);
    } else {
        hough_g_k<false><<<nblk, 256, 0, stream>>>(mask, mask, nullptr, out, nba);
    }
}

// Round 7
// 137.059 us; speedup vs baseline: 1.0839x; 1.0839x over previous
//
#include <hip/hip_runtime.h>
#include <math.h>

#define NUM_A 90
#define RBINS 727      // 2*363 + 1
#define HDIM  256
#define WDIM  256
#define RMIN  181      // lowest bin ever touched
#define RACT  365      // active bins: 181..545
#define BINS_PAD 368
#define STRIPS 4
#define GRP (BINS_PAD * STRIPS)   // 1472 threads per (b,a) = 23 waves exactly

// ---------------- angle table: tab[2a]=cos, tab[2a+1]=sin ----------------
__global__ void angles_k(float* __restrict__ tab) {
    int a = threadIdx.x;
    if (a < NUM_A) {
        double th = (double)a * (3.14159265358979323846 / 90.0);
        tab[2 * a]     = (float)cos(th);
        tab[2 * a + 1] = (float)sin(th);
    }
}

// ---------------- transpose: maskT[b][x][y] = mask[b][y][x] ----------------
__global__ __launch_bounds__(256) void transpose_k(const float* __restrict__ in,
                                                   float* __restrict__ out) {
    __shared__ float tile[32][33];
    int b = blockIdx.z;
    const float* ib = in  + (size_t)b * (HDIM * WDIM);
    float*       ob = out + (size_t)b * (HDIM * WDIM);
    int x0 = blockIdx.x * 32, y0 = blockIdx.y * 32;
    int tx = threadIdx.x, ty = threadIdx.y;
#pragma unroll
    for (int j = ty; j < 32; j += 8)
        tile[j][tx] = ib[(size_t)(y0 + j) * WDIM + (x0 + tx)];
    __syncthreads();
#pragma unroll
    for (int j = ty; j < 32; j += 8)
        ob[(size_t)(x0 + j) * HDIM + (y0 + tx)] = tile[tx][j];
}

// 12-byte vector load (global_load_dwordx3), 4-byte aligned
typedef float f3v __attribute__((ext_vector_type(3)));
typedef f3v __attribute__((aligned(4))) f3u;

// ---------------- gather hough, strip-split, unrolled x4 + tail ----------------
// out[ba, r] = sum_{i,j} m * max(0, 1 - |t - r|), t = (i-128)ci + (j-128)cj + 363.
// Lane owns (bin r, strip m of 4); strips use the EXACT partition of [jl, jh)
// (R4-proven under graph replay): js = jl + (m*len>>2), je = jl + ((m+1)*len>>2).
// Main loop: chunks of 4 rows with 4 independent dwordx3 load->fma chains;
// <=3 leftover rows in a scalar tail. No padding rows, no strip overlap.
template<bool FAST>
__global__ __launch_bounds__(256) void hough_g_k(const float* __restrict__ srcA,
                                                 const float* __restrict__ srcB,
                                                 const float* __restrict__ tab,
                                                 float* __restrict__ out,
                                                 int nba) {
    int gtid = blockIdx.x * 256 + threadIdx.x;
    int grp  = gtid / GRP;                 // wave-uniform (GRP % 64 == 0)
    if (grp >= nba) return;
    int k    = gtid - grp * GRP;
    int ba   = __builtin_amdgcn_readfirstlane(grp);
    int b    = ba / NUM_A;
    int a    = ba - b * NUM_A;

    float c, s;
    if (FAST) { c = tab[2 * a]; s = tab[2 * a + 1]; }
    else {
        double th = (double)a * (3.14159265358979323846 / 90.0);
        c = (float)cos(th); s = (float)sin(th);
    }

    bool  xs = fabsf(c) >= fabsf(s);       // solve axis = larger coeff
    float ci = xs ? c : s;
    float cj = xs ? s : c;
    const float* src = (FAST ? (xs ? srcA : srcB) : srcA) + (size_t)b * (HDIM * WDIM);

    int   bin = k >> 2;                    // STRIPS = 4
    int   m   = k & 3;
    int   r   = RMIN + bin;
    float rf  = (float)r;
    bool  active = bin < RACT;

    // active j-range: rows whose in-image t-span [base+p, base+q] hits (r-1,r+1)
    float inv  = 1.0f / ci;                // |ci| >= 0.707
    float ainv = fabsf(inv);
    float p = fminf(-128.0f * ci, 127.0f * ci);
    float q = fmaxf(-128.0f * ci, 127.0f * ci);
    int jl, jh;
    float acj = fabsf(cj);
    if (acj > 1e-5f) {
        float invj = 1.0f / cj;
        float jA = (rf + 1.0f - p - 363.0f) * invj + 128.0f;
        float jB = (rf - 1.0f - q - 363.0f) * invj + 128.0f;
        float jmn = fminf(jA, jB) - 1.0f;   // widen: weights self-guard extras
        float jmx = fmaxf(jA, jB) + 2.0f;
        jl = (int)fminf(fmaxf(jmn, 0.0f), 256.0f);
        jh = (int)fminf(fmaxf(jmx, 0.0f), 256.0f);
    } else {                               // cj ~ 0: t j-independent
        bool any = (363.0f + q > rf - 1.01f) && (363.0f + p < rf + 1.01f);
        jl = 0; jh = any ? 256 : 0;
    }
    if (!active) { jl = 0; jh = 0; }
    int len = jh - jl;                     // >= 0

    // EXACT partition (R4-proven): no overlap, no gap, no padding rows
    int js = jl + ((m * len) >> 2);
    int je = jl + (((m + 1) * len) >> 2);

    // lo(j) = LO0 + j*dlo (lower i-edge of window), z(j) = Z0 + j*cj
    // (u0 = i0f*ci + z = t(i0,j) - r). fma-from-base per chunk, adds within.
    float dlo = -cj * inv;
    float LO0 = 128.0f + (rf - 363.0f) * inv - ainv + 128.0f * cj * inv;
    float Z0  = 363.0f - rf - 128.0f * cj - 128.0f * ci;
    float ci2 = ci + ci;
    float dlo2 = dlo + dlo, dlo3 = dlo2 + dlo;
    float cj2  = cj + cj,   cj3  = cj2 + cj;

    float acc = 0.0f;
    int j = js;
    int je4 = js + ((je - js) & ~3);
    for (; j < je4; j += 4) {
        float jf  = (float)j;
        float lo0 = fmaf(jf, dlo, LO0);
        float z0  = fmaf(jf, cj, Z0);
        float lo1 = lo0 + dlo,  lo2 = lo0 + dlo2, lo3 = lo0 + dlo3;
        float z1  = z0 + cj,    z2  = z0 + cj2,   z3  = z0 + cj3;

        float f0 = __builtin_amdgcn_fmed3f(ceilf(lo0), 0.0f, 253.0f);
        float f1 = __builtin_amdgcn_fmed3f(ceilf(lo1), 0.0f, 253.0f);
        float f2 = __builtin_amdgcn_fmed3f(ceilf(lo2), 0.0f, 253.0f);
        float f3 = __builtin_amdgcn_fmed3f(ceilf(lo3), 0.0f, 253.0f);
        int i0 = (int)f0, i1 = (int)f1, i2 = (int)f2, i3 = (int)f3;

        f3v mA, mB, mC, mD;
        if (FAST || xs) {                  // solve axis contiguous: 4 indep loads
            mA = *(const f3u*)(src + (((size_t)j + 0) << 8) + i0);
            mB = *(const f3u*)(src + (((size_t)j + 1) << 8) + i1);
            mC = *(const f3u*)(src + (((size_t)j + 2) << 8) + i2);
            mD = *(const f3u*)(src + (((size_t)j + 3) << 8) + i3);
        } else {                           // fallback: strided
            const float* p0 = src + (j + 0) + ((size_t)i0 << 8);
            const float* p1 = src + (j + 1) + ((size_t)i1 << 8);
            const float* p2 = src + (j + 2) + ((size_t)i2 << 8);
            const float* p3 = src + (j + 3) + ((size_t)i3 << 8);
            mA = f3v{p0[0], p0[256], p0[512]};
            mB = f3v{p1[0], p1[256], p1[512]};
            mC = f3v{p2[0], p2[256], p2[512]};
            mD = f3v{p3[0], p3[256], p3[512]};
        }

        float uA = fmaf(f0, ci, z0);
        acc = fmaf(mA.x, fmaxf(1.0f - fabsf(uA), 0.0f), acc);
        acc = fmaf(mA.y, fmaxf(1.0f - fabsf(uA + ci), 0.0f), acc);
        acc = fmaf(mA.z, fmaxf(1.0f - fabsf(uA + ci2), 0.0f), acc);
        float uB = fmaf(f1, ci, z1);
        acc = fmaf(mB.x, fmaxf(1.0f - fabsf(uB), 0.0f), acc);
        acc = fmaf(mB.y, fmaxf(1.0f - fabsf(uB + ci), 0.0f), acc);
        acc = fmaf(mB.z, fmaxf(1.0f - fabsf(uB + ci2), 0.0f), acc);
        float uC = fmaf(f2, ci, z2);
        acc = fmaf(mC.x, fmaxf(1.0f - fabsf(uC), 0.0f), acc);
        acc = fmaf(mC.y, fmaxf(1.0f - fabsf(uC + ci), 0.0f), acc);
        acc = fmaf(mC.z, fmaxf(1.0f - fabsf(uC + ci2), 0.0f), acc);
        float uD = fmaf(f3, ci, z3);
        acc = fmaf(mD.x, fmaxf(1.0f - fabsf(uD), 0.0f), acc);
        acc = fmaf(mD.y, fmaxf(1.0f - fabsf(uD + ci), 0.0f), acc);
        acc = fmaf(mD.z, fmaxf(1.0f - fabsf(uD + ci2), 0.0f), acc);
    }
    for (; j < je; ++j) {                  // tail: <=3 rows
        float jf  = (float)j;
        float lo0 = fmaf(jf, dlo, LO0);
        float z0  = fmaf(jf, cj, Z0);
        float f0  = __builtin_amdgcn_fmed3f(ceilf(lo0), 0.0f, 253.0f);
        int   i0  = (int)f0;
        f3v mA;
        if (FAST || xs) {
            mA = *(const f3u*)(src + ((size_t)j << 8) + i0);
        } else {
            const float* p0 = src + j + ((size_t)i0 << 8);
            mA = f3v{p0[0], p0[256], p0[512]};
        }
        float uA = fmaf(f0, ci, z0);
        acc = fmaf(mA.x, fmaxf(1.0f - fabsf(uA), 0.0f), acc);
        acc = fmaf(mA.y, fmaxf(1.0f - fabsf(uA + ci), 0.0f), acc);
        acc = fmaf(mA.z, fmaxf(1.0f - fabsf(uA + ci2), 0.0f), acc);
    }

    // reduce the 4 strips (adjacent lanes), lane m==0 stores
    acc += __shfl_xor(acc, 1);
    acc += __shfl_xor(acc, 2);
    if (active && m == 0)
        out[(size_t)ba * RBINS + r] = acc;
}

extern "C" void kernel_launch(void* const* d_in, const int* in_sizes, int n_in,
                              void* d_out, int out_size, void* d_ws, size_t ws_size,
                              hipStream_t stream) {
    const float* mask = (const float*)d_in[0];
    float* out = (float*)d_out;
    int B = in_sizes[0] / (HDIM * WDIM);   // 16
    int nba = B * NUM_A;

    size_t needT = (size_t)B * HDIM * WDIM * sizeof(float);
    size_t needW = needT + 2 * NUM_A * sizeof(float);
    int fast = (d_ws != nullptr && ws_size >= needW) ? 1 : 0;
    float* maskT = (float*)d_ws;
    float* tab   = (float*)((char*)d_ws + needT);

    // zero the never-touched rho bins once per call (also covers len==0 bins)
    hipMemsetAsync(d_out, 0, (size_t)out_size * sizeof(float), stream);

    int nthreads = nba * GRP;
    int nblk = (nthreads + 255) / 256;

    if (fast) {
        transpose_k<<<dim3(WDIM / 32, HDIM / 32, B), dim3(32, 8), 0, stream>>>(mask, maskT);
        angles_k<<<1, 128, 0, stream>>>(tab);
        hough_g_k<true><<<nblk, 256, 0, stream>>>(mask, maskT, tab, out, nba);
    } else {
        hough_g_k<false><<<nblk, 256, 0, stream>>>(mask, mask, nullptr, out, nba);
    }
}

// Round 8
// 114.497 us; speedup vs baseline: 1.2975x; 1.1971x over previous
//
#include <hip/hip_runtime.h>
#include <math.h>

#define NUM_A 90
#define RBINS 727      // 2*363 + 1
#define HDIM  256
#define WDIM  256
#define RMIN  181      // lowest bin ever touched
#define RACT  365      // active bins: 181..545
#define TPB   768      // 368 bins x 2 strips (+32 pad) = 12 waves
#define PHROWS   64
#define PHFLOATS (PHROWS * 256)   // 16384 floats = 64 KB

// ---------------- angle table: tab[2a]=cos, tab[2a+1]=sin ----------------
__global__ void angles_k(float* __restrict__ tab) {
    int a = threadIdx.x;
    if (a < NUM_A) {
        double th = (double)a * (3.14159265358979323846 / 90.0);
        tab[2 * a]     = (float)cos(th);
        tab[2 * a + 1] = (float)sin(th);
    }
}

// ---------------- transpose: maskT[b][x][y] = mask[b][y][x] ----------------
__global__ __launch_bounds__(256) void transpose_k(const float* __restrict__ in,
                                                   float* __restrict__ out) {
    __shared__ float tile[32][33];
    int b = blockIdx.z;
    const float* ib = in  + (size_t)b * (HDIM * WDIM);
    float*       ob = out + (size_t)b * (HDIM * WDIM);
    int x0 = blockIdx.x * 32, y0 = blockIdx.y * 32;
    int tx = threadIdx.x, ty = threadIdx.y;
#pragma unroll
    for (int j = ty; j < 32; j += 8)
        tile[j][tx] = ib[(size_t)(y0 + j) * WDIM + (x0 + tx)];
    __syncthreads();
#pragma unroll
    for (int j = ty; j < 32; j += 8)
        ob[(size_t)(x0 + j) * HDIM + (y0 + tx)] = tile[tx][j];
}

// ---------------- LDS-staged gather hough ----------------
// One block per (b,a). 4 phases: stage 64 solve-layout rows (64 KB) into LDS,
// then each lane (bin r, strip m of 2) gathers its 3 taps per row from LDS.
// Exact strip partition of [jl,jh) (R4-proven), intersected with the phase
// band. Scattered reads hit LDS banks (~2-way) instead of the TA cacheline
// serializer that bounded the previous kernel.
__global__ __launch_bounds__(TPB, 6) void hough_lds_k(const float* __restrict__ srcA,
                                                      const float* __restrict__ srcB,
                                                      const float* __restrict__ tab,
                                                      float* __restrict__ out) {
    __shared__ float tile[PHFLOATS];
    int ba = blockIdx.x;
    int b  = ba / NUM_A;
    int a  = ba - b * NUM_A;

    float c = tab[2 * a], s = tab[2 * a + 1];
    bool  xs = fabsf(c) >= fabsf(s);       // solve axis = larger coeff
    float ci = xs ? c : s;
    float cj = xs ? s : c;
    const float* src = (xs ? srcA : srcB) + (size_t)b * (HDIM * WDIM);

    int   tid = threadIdx.x;
    int   bin = tid >> 1;                  // STRIPS = 2
    int   m   = tid & 1;
    int   r   = RMIN + bin;
    float rf  = (float)r;
    bool  active = bin < RACT;

    // active j-range: rows whose in-image t-span [base+p, base+q] hits (r-1,r+1)
    float inv  = 1.0f / ci;                // |ci| >= 0.707
    float ainv = fabsf(inv);
    float p = fminf(-128.0f * ci, 127.0f * ci);
    float q = fmaxf(-128.0f * ci, 127.0f * ci);
    int jl, jh;
    float acj = fabsf(cj);
    if (acj > 1e-5f) {
        float invj = 1.0f / cj;
        float jA = (rf + 1.0f - p - 363.0f) * invj + 128.0f;
        float jB = (rf - 1.0f - q - 363.0f) * invj + 128.0f;
        float jmn = fminf(jA, jB) - 1.0f;   // widen: weights self-guard extras
        float jmx = fmaxf(jA, jB) + 2.0f;
        jl = (int)fminf(fmaxf(jmn, 0.0f), 256.0f);
        jh = (int)fminf(fmaxf(jmx, 0.0f), 256.0f);
    } else {                               // cj ~ 0: t j-independent
        bool any = (363.0f + q > rf - 1.01f) && (363.0f + p < rf + 1.01f);
        jl = 0; jh = any ? 256 : 0;
    }
    if (!active) { jl = 0; jh = 0; }
    int len = jh - jl;

    // EXACT strip partition (no overlap, no gap, no padding rows)
    int ls = jl + ((m * len) >> 1);
    int le = jl + (((m + 1) * len) >> 1);

    float dlo  = -cj * inv;
    float LO0  = 128.0f + (rf - 363.0f) * inv - ainv + 128.0f * cj * inv;
    float Z0   = 363.0f - rf - 128.0f * cj - 128.0f * ci;
    float ci2  = ci + ci;
    float dlo2 = dlo + dlo, dlo3 = dlo2 + dlo;
    float cjf2 = cj + cj,   cjf3 = cjf2 + cj;

    float acc = 0.0f;
    for (int ph = 0; ph < 4; ++ph) {
        if (ph) __syncthreads();           // prior-phase LDS reads complete
        // stage rows [ph*64, ph*64+64): linear, wave-lane-contiguous 16B units
        const float* gph = src + ph * PHFLOATS;
        for (int u = tid; u < PHFLOATS / 4; u += TPB) {
            __builtin_amdgcn_global_load_lds(
                (const __attribute__((address_space(1))) unsigned int*)gph + (size_t)u * 4,
                (__attribute__((address_space(3))) unsigned int*)tile + (size_t)u * 4,
                16, 0, 0);
        }
        __syncthreads();                   // staging complete (vmcnt drained)

        int ph64 = ph << 6;
        int jsp = ls > ph64 ? ls : ph64;
        int jep = le < ph64 + 64 ? le : ph64 + 64;
        if (jep <= jsp) continue;

        int j = jsp;
        int jend4 = jsp + ((jep - jsp) & ~3);
        for (; j < jend4; j += 4) {
            float jf  = (float)j;
            float lo0 = fmaf(jf, dlo, LO0);
            float z0  = fmaf(jf, cj, Z0);
            float lo1 = lo0 + dlo,  lo2 = lo0 + dlo2, lo3 = lo0 + dlo3;
            float z1  = z0 + cj,    z2  = z0 + cjf2,  z3  = z0 + cjf3;

            float f0 = __builtin_amdgcn_fmed3f(ceilf(lo0), 0.0f, 253.0f);
            float f1 = __builtin_amdgcn_fmed3f(ceilf(lo1), 0.0f, 253.0f);
            float f2 = __builtin_amdgcn_fmed3f(ceilf(lo2), 0.0f, 253.0f);
            float f3 = __builtin_amdgcn_fmed3f(ceilf(lo3), 0.0f, 253.0f);
            int i0 = (int)f0, i1 = (int)f1, i2 = (int)f2, i3 = (int)f3;

            int rw = (j - ph64) << 8;
            const float* p0 = tile + rw + i0;
            const float* p1 = tile + rw + 256 + i1;
            const float* p2 = tile + rw + 512 + i2;
            const float* p3 = tile + rw + 768 + i3;
            float a0 = p0[0], b0 = p0[1], c0 = p0[2];
            float a1 = p1[0], b1 = p1[1], c1 = p1[2];
            float a2 = p2[0], b2 = p2[1], c2 = p2[2];
            float a3 = p3[0], b3 = p3[1], c3 = p3[2];

            float u0 = fmaf(f0, ci, z0);
            acc = fmaf(a0, fmaxf(1.0f - fabsf(u0), 0.0f), acc);
            acc = fmaf(b0, fmaxf(1.0f - fabsf(u0 + ci), 0.0f), acc);
            acc = fmaf(c0, fmaxf(1.0f - fabsf(u0 + ci2), 0.0f), acc);
            float u1 = fmaf(f1, ci, z1);
            acc = fmaf(a1, fmaxf(1.0f - fabsf(u1), 0.0f), acc);
            acc = fmaf(b1, fmaxf(1.0f - fabsf(u1 + ci), 0.0f), acc);
            acc = fmaf(c1, fmaxf(1.0f - fabsf(u1 + ci2), 0.0f), acc);
            float u2 = fmaf(f2, ci, z2);
            acc = fmaf(a2, fmaxf(1.0f - fabsf(u2), 0.0f), acc);
            acc = fmaf(b2, fmaxf(1.0f - fabsf(u2 + ci), 0.0f), acc);
            acc = fmaf(c2, fmaxf(1.0f - fabsf(u2 + ci2), 0.0f), acc);
            float u3 = fmaf(f3, ci, z3);
            acc = fmaf(a3, fmaxf(1.0f - fabsf(u3), 0.0f), acc);
            acc = fmaf(b3, fmaxf(1.0f - fabsf(u3 + ci), 0.0f), acc);
            acc = fmaf(c3, fmaxf(1.0f - fabsf(u3 + ci2), 0.0f), acc);
        }
        for (; j < jep; ++j) {             // tail: <=3 rows per phase
            float jf  = (float)j;
            float lo0 = fmaf(jf, dlo, LO0);
            float z0  = fmaf(jf, cj, Z0);
            float f0  = __builtin_amdgcn_fmed3f(ceilf(lo0), 0.0f, 253.0f);
            int   i0  = (int)f0;
            const float* p0 = tile + ((j - ph64) << 8) + i0;
            float a0 = p0[0], b0 = p0[1], c0 = p0[2];
            float u0 = fmaf(f0, ci, z0);
            acc = fmaf(a0, fmaxf(1.0f - fabsf(u0), 0.0f), acc);
            acc = fmaf(b0, fmaxf(1.0f - fabsf(u0 + ci), 0.0f), acc);
            acc = fmaf(c0, fmaxf(1.0f - fabsf(u0 + ci2), 0.0f), acc);
        }
    }

    // reduce the 2 strips (adjacent lanes), lane m==0 stores
    acc += __shfl_xor(acc, 1);
    if (active && m == 0)
        out[(size_t)ba * RBINS + r] = acc;
}

// ---------------- fallback (no workspace): R7-proven global-gather ----------------
typedef float f3v __attribute__((ext_vector_type(3)));
typedef f3v __attribute__((aligned(4))) f3u;
#define FB_GRP (368 * 4)

__global__ __launch_bounds__(256) void hough_fb_k(const float* __restrict__ src0,
                                                  float* __restrict__ out, int nba) {
    int gtid = blockIdx.x * 256 + threadIdx.x;
    int grp  = gtid / FB_GRP;
    if (grp >= nba) return;
    int k    = gtid - grp * FB_GRP;
    int ba   = __builtin_amdgcn_readfirstlane(grp);
    int b    = ba / NUM_A;
    int a    = ba - b * NUM_A;
    double th = (double)a * (3.14159265358979323846 / 90.0);
    float c = (float)cos(th), s = (float)sin(th);
    bool  xs = fabsf(c) >= fabsf(s);
    float ci = xs ? c : s, cj = xs ? s : c;
    const float* src = src0 + (size_t)b * (HDIM * WDIM);
    int   bin = k >> 2, m = k & 3;
    int   r = RMIN + bin;
    float rf = (float)r;
    bool  active = bin < RACT;
    float inv = 1.0f / ci, ainv = fabsf(inv);
    float p = fminf(-128.0f * ci, 127.0f * ci);
    float q = fmaxf(-128.0f * ci, 127.0f * ci);
    int jl, jh;
    float acj = fabsf(cj);
    if (acj > 1e-5f) {
        float invj = 1.0f / cj;
        float jA = (rf + 1.0f - p - 363.0f) * invj + 128.0f;
        float jB = (rf - 1.0f - q - 363.0f) * invj + 128.0f;
        jl = (int)fminf(fmaxf(fminf(jA, jB) - 1.0f, 0.0f), 256.0f);
        jh = (int)fminf(fmaxf(fmaxf(jA, jB) + 2.0f, 0.0f), 256.0f);
    } else {
        bool any = (363.0f + q > rf - 1.01f) && (363.0f + p < rf + 1.01f);
        jl = 0; jh = any ? 256 : 0;
    }
    if (!active) { jl = 0; jh = 0; }
    int len = jh - jl;
    int js = jl + ((m * len) >> 2);
    int je = jl + (((m + 1) * len) >> 2);
    float dlo = -cj * inv;
    float LO0 = 128.0f + (rf - 363.0f) * inv - ainv + 128.0f * cj * inv;
    float Z0  = 363.0f - rf - 128.0f * cj - 128.0f * ci;
    float ci2 = ci + ci;
    float acc = 0.0f;
    for (int j = js; j < je; ++j) {
        float jf  = (float)j;
        float lo0 = fmaf(jf, dlo, LO0);
        float z0  = fmaf(jf, cj, Z0);
        float f0  = __builtin_amdgcn_fmed3f(ceilf(lo0), 0.0f, 253.0f);
        int   i0  = (int)f0;
        float a0, b0, c0;
        if (xs) {
            f3v mm = *(const f3u*)(src + ((size_t)j << 8) + i0);
            a0 = mm.x; b0 = mm.y; c0 = mm.z;
        } else {
            const float* p0 = src + j + ((size_t)i0 << 8);
            a0 = p0[0]; b0 = p0[256]; c0 = p0[512];
        }
        float u0 = fmaf(f0, ci, z0);
        acc = fmaf(a0, fmaxf(1.0f - fabsf(u0), 0.0f), acc);
        acc = fmaf(b0, fmaxf(1.0f - fabsf(u0 + ci), 0.0f), acc);
        acc = fmaf(c0, fmaxf(1.0f - fabsf(u0 + ci2), 0.0f), acc);
    }
    acc += __shfl_xor(acc, 1);
    acc += __shfl_xor(acc, 2);
    if (active && m == 0)
        out[(size_t)ba * RBINS + r] = acc;
}

extern "C" void kernel_launch(void* const* d_in, const int* in_sizes, int n_in,
                              void* d_out, int out_size, void* d_ws, size_t ws_size,
                              hipStream_t stream) {
    const float* mask = (const float*)d_in[0];
    float* out = (float*)d_out;
    int B = in_sizes[0] / (HDIM * WDIM);   // 16
    int nba = B * NUM_A;

    size_t needT = (size_t)B * HDIM * WDIM * sizeof(float);
    size_t needW = needT + 2 * NUM_A * sizeof(float);
    int fast = (d_ws != nullptr && ws_size >= needW) ? 1 : 0;
    float* maskT = (float*)d_ws;
    float* tab   = (float*)((char*)d_ws + needT);

    // zero the never-touched rho bins once per call (also covers len==0 bins)
    hipMemsetAsync(d_out, 0, (size_t)out_size * sizeof(float), stream);

    if (fast) {
        transpose_k<<<dim3(WDIM / 32, HDIM / 32, B), dim3(32, 8), 0, stream>>>(mask, maskT);
        angles_k<<<1, 128, 0, stream>>>(tab);
        hough_lds_k<<<nba, TPB, 0, stream>>>(mask, maskT, tab, out);
    } else {
        int nthreads = nba * FB_GRP;
        hough_fb_k<<<(nthreads + 255) / 256, 256, 0, stream>>>(mask, out, nba);
    }
}